// Round 10
// baseline (47.965 us; speedup 1.0000x reference)
//
#include <hip/hip_runtime.h>
#include <math.h>

#define N_BOIDS 8192
typedef float f32x2 __attribute__((ext_vector_type(2)));
typedef float f32x4 __attribute__((ext_vector_type(4)));

// ---- binning
constexpr int   NC    = 16;
constexpr int   NCELL = NC * NC;            // 256
constexpr int   CHUNK = 256;
constexpr int   NBLK  = N_BOIDS / CHUNK;    // 32
constexpr int   MAXP  = 8;                  // boids per wave (fast path: n<=64/cell)
constexpr int   WLCAP = 4096;               // LDS worklist capacity (float4)
// ws layout
constexpr size_t CS_OFF   = 0;              // 257*4 -> pad 4096
constexpr size_t SORT_OFF = 4096;           // 8192*16
constexpr size_t SIDX_OFF = 135168;         // 8192*4
constexpr size_t WS_NEED  = 167936;

// f32 roundings of the Python doubles 0.02**2 and 0.2**2
constexpr float SEP_R2  = 4.0000000000000008e-04f;
constexpr float PERC_R2 = 4.0000000000000001e-02f;
constexpr float EPSF    = 1e-08f;

__device__ __forceinline__ int cell_of(float px, float py) {
    int cx = (int)(px * 16.0f); cx = cx > 15 ? 15 : (cx < 0 ? 0 : cx);
    int cy = (int)(py * 16.0f); cy = cy > 15 ? 15 : (cy < 0 ? 0 : cy);
    return cy * NC + cx;
}

// ---- fused sort: hist(all) + scan + stable scatter of own chunk
__global__ __launch_bounds__(CHUNK) void sort_all(
    const float* __restrict__ pos, const float* __restrict__ vel,
    int* __restrict__ cs, float4* __restrict__ sorted4, int* __restrict__ sidx)
{
    __shared__ int tot[NCELL];   // global per-cell counts
    __shared__ int part[NCELL];  // counts among boids in chunks < b
    __shared__ int scan[NCELL];  // inclusive scan of tot
    __shared__ int cid[CHUNK];
    const int c = threadIdx.x;
    const int b = blockIdx.x;
    tot[c] = 0; part[c] = 0;
    __syncthreads();
    const int lim = b * CHUNK;
    for (int i = c; i < N_BOIDS; i += CHUNK) {
        const int cc = cell_of(pos[2 * i], pos[2 * i + 1]);
        atomicAdd(&tot[cc], 1);                 // count only: order-independent
        if (i < lim) atomicAdd(&part[cc], 1);
    }
    __syncthreads();
    scan[c] = tot[c];
    __syncthreads();
#pragma unroll
    for (int off = 1; off < NCELL; off <<= 1) {
        int v = (c >= off) ? scan[c - off] : 0;
        __syncthreads();
        scan[c] += v;
        __syncthreads();
    }
    if (b == 0) {
        cs[c] = scan[c] - tot[c];
        if (c == NCELL - 1) cs[NCELL] = scan[NCELL - 1];
    }
    // stable scatter of own chunk: order = (cell, chunk, tid)
    const int i = lim + c;
    const float px = pos[2 * i], py = pos[2 * i + 1];
    const int myc = cell_of(px, py);
    cid[c] = myc;
    __syncthreads();
    int rank = 0;
    for (int t2 = 0; t2 < c; ++t2) rank += (cid[t2] == myc) ? 1 : 0;
    const int slot = (scan[myc] - tot[myc]) + part[myc] + rank;
    float4 o; o.x = px; o.y = py; o.z = vel[2 * i]; o.w = vel[2 * i + 1];
    sorted4[slot] = o;
    sidx[slot]    = i;
}

// ---- exact 21-instr pair accumulate (same math as every round since R5)
__device__ __forceinline__ void pair_acc(
    const float4& q, float px, float py, float inv,
    float& n, float& sx, float& sy, float& vx, float& vy, float& cx, float& cy)
{
    float dx, dy, ta, tb, m;
    asm("v_sub_f32   %[dx], %[qx], %[px]\n\t"
        "v_sub_f32   %[dy], %[qy], %[py]\n\t"
        "v_rndne_f32 %[ta], %[dx]\n\t"
        "v_rndne_f32 %[tb], %[dy]\n\t"
        "v_sub_f32   %[dx], %[dx], %[ta]\n\t"
        "v_sub_f32   %[dy], %[dy], %[tb]\n\t"
        "v_mul_f32   %[ta], %[dx], %[dx]\n\t"
        "v_mul_f32   %[tb], %[dy], %[dy]\n\t"
        "v_add_f32   %[ta], %[ta], %[tb]\n\t"   // d2, exact RN mul/mul/add
        "v_max_f32   %[ta], %[ta], %[inv]\n\t"  // pad lanes -> 1e9
        "v_cmp_ge_f32 vcc, %[vperc], %[ta]\n\t"
        "v_cndmask_b32 %[m], 0, 1.0, vcc\n\t"
        "v_add_f32   %[n], %[n], %[m]\n\t"
        "v_fmac_f32  %[vx], %[m], %[qz]\n\t"
        "v_fmac_f32  %[vy], %[m], %[qw]\n\t"
        "v_fmac_f32  %[cx], %[m], %[dx]\n\t"
        "v_fmac_f32  %[cy], %[m], %[dy]\n\t"
        "v_cmp_ge_f32 vcc, %[vsep], %[ta]\n\t"
        "v_cndmask_b32 %[m], 0, 1.0, vcc\n\t"
        "v_fma_f32   %[sx], -%[m], %[dx], %[sx]\n\t"
        "v_fma_f32   %[sy], -%[m], %[dy], %[sy]\n\t"
        : [dx] "=&v"(dx), [dy] "=&v"(dy), [ta] "=&v"(ta),
          [tb] "=&v"(tb), [m] "=&v"(m),
          [n] "+v"(n), [sx] "+v"(sx), [sy] "+v"(sy),
          [vx] "+v"(vx), [vy] "+v"(vy), [cx] "+v"(cx), [cy] "+v"(cy)
        : [qx] "v"(q.x), [qy] "v"(q.y), [qz] "v"(q.z), [qw] "v"(q.w),
          [px] "v"(px), [py] "v"(py),
          [vperc] "v"(PERC_R2), [vsep] "v"(SEP_R2), [inv] "v"(inv)
        : "vcc");
}

__device__ __forceinline__ void bfly7(float& a, float& b, float& c, float& d,
                                      float& e, float& f, float& g)
{
#pragma unroll
    for (int m = 1; m < 64; m <<= 1) {
        a += __shfl_xor(a, m); b += __shfl_xor(b, m); c += __shfl_xor(c, m);
        d += __shfl_xor(d, m); e += __shfl_xor(e, m); f += __shfl_xor(f, m);
        g += __shfl_xor(g, m);
    }
}

__device__ __forceinline__ void finalize_core(
    float vix, float viy, const f32x2 nz,
    float ws, float wa, float wc, float wn,
    float sx, float sy, float vx, float vy, float cx, float cy, float cntall,
    float* __restrict__ out, int orig)
{
    const float cnt = cntall - 1.0f;  // remove self (d2==0 passed the mask)
    float ns  = fmaxf(sqrtf(sx * sx + sy * sy), EPSF);
    float ssx = sx / ns, ssy = sy / ns;
    float vax = (vx - vix) / cnt - vix;
    float vay = (vy - viy) / cnt - viy;
    float na  = fmaxf(sqrtf(vax * vax + vay * vay), EPSF);
    float sax = vax / na, say = vay / na;
    float pax = cx / cnt, pay = cy / cnt;
    float nc  = fmaxf(sqrtf(pax * pax + pay * pay), EPSF);
    float scx = pax / nc, scy = pay / nc;
    float ax = ws * ssx + wa * sax + wc * scx;
    float ay = ws * ssy + wa * say + wc * scy;
    ax += wn * nz.x;
    ay += wn * nz.y;
    const float nn = sqrtf(ax * ax + ay * ay);
    if (nn > 1.0f) {
        const float s = 1.0f / fmaxf(nn, EPSF);
        ax *= s; ay *= s;
    }
    out[2 * orig]     = ax;
    out[2 * orig + 1] = ay;
}

// ---- main: one block per cell; LDS worklist of the 69-cell neighbor disc
__global__ __launch_bounds__(512) void boids_cell(
    const float4* __restrict__ sorted4,
    const int* __restrict__ sidx,
    const int* __restrict__ cs,
    const f32x2* __restrict__ noise,
    const float* __restrict__ w_sep, const float* __restrict__ w_ali,
    const float* __restrict__ w_coh, const float* __restrict__ w_noise,
    float* __restrict__ out)
{
    __shared__ int    cs_l[NCELL + 1];
    __shared__ int    seg_src[20], seg_dst[20];   // dst = worklist prefix start
    __shared__ int    nseg_s, total_s;
    __shared__ float4 wl[WLCAP];                  // 64 KB

    const int tid  = threadIdx.x;
    const int lane = tid & 63;
    const int wid  = tid >> 6;                    // 0..7

    for (int i = tid; i < NCELL + 1; i += 512) cs_l[i] = cs[i];
    __syncthreads();

    const int cellId = blockIdx.x;
    const int cx = cellId & (NC - 1), cy = cellId >> 4;

    if (tid == 0) {
        // exact neighbor disc for reach 0.2002 on a 1/16 grid
        const int HW[9] = {2, 3, 4, 4, 4, 4, 4, 3, 2};
        int ns = 0, tot = 0;
        for (int oy = -4; oy <= 4; ++oy) {
            const int ry = (cy + oy) & (NC - 1);
            const int rb = ry * NC;
            const int hw = HW[oy + 4];
            const int ncl = 2 * hw + 1;
            const int xs = (cx - hw) & (NC - 1);
            const int lA = (ncl < NC - xs) ? ncl : (NC - xs);
            const int sA = cs_l[rb + xs], eA = cs_l[rb + xs + lA];
            if (eA > sA) { seg_src[ns] = sA; seg_dst[ns] = tot; tot += eA - sA; ++ns; }
            const int lB = ncl - lA;
            if (lB > 0) {
                const int sB = cs_l[rb], eB = cs_l[rb + lB];
                if (eB > sB) { seg_src[ns] = sB; seg_dst[ns] = tot; tot += eB - sB; ++ns; }
            }
        }
        nseg_s = ns; total_s = tot; seg_dst[ns] = tot;  // sentinel
    }
    __syncthreads();
    const int nseg = nseg_s, total = total_s;
    const int cstart = cs_l[cellId], cend = cs_l[cellId + 1];
    const int n = cend - cstart;
    int npass = (n - wid + 7) >> 3;
    if (npass < 0) npass = 0;
    if (npass > MAXP) npass = MAXP;

    float Px[MAXP], Py[MAXP], Vx[MAXP], Vy[MAXP];
    float an[MAXP], asx[MAXP], asy[MAXP], avx[MAXP], avy[MAXP], acx[MAXP], acy[MAXP];
#pragma unroll
    for (int p = 0; p < MAXP; ++p) {
        Px[p] = 0.f; Py[p] = 0.f; Vx[p] = 0.f; Vy[p] = 0.f;
        an[p] = 0.f; asx[p] = 0.f; asy[p] = 0.f;
        avx[p] = 0.f; avy[p] = 0.f; acx[p] = 0.f; acy[p] = 0.f;
    }
#pragma unroll
    for (int p = 0; p < MAXP; ++p) {
        if (p < npass) {
            const float4 I = sorted4[cstart + wid + p * 8];
            Px[p] = I.x; Py[p] = I.y; Vx[p] = I.z; Vy[p] = I.w;
        }
    }

    for (int base = 0; base < total; base += WLCAP) {
        const int clen = (total - base < WLCAP) ? (total - base) : WLCAP;
        for (int g = tid; g < clen; g += 512) {
            const int gg = base + g;
            int s = 0;
            while (s + 1 < nseg && gg >= seg_dst[s + 1]) ++s;
            wl[g] = sorted4[seg_src[s] + (gg - seg_dst[s])];
        }
        __syncthreads();
        for (int j0 = 0; j0 < clen; j0 += 64) {
            const int   idx = j0 + lane;
            const float inv = (idx < clen) ? 0.0f : 1e9f;
            const float4 q  = wl[(idx < clen) ? idx : (clen - 1)];
#define PB(p) pair_acc(q, Px[p], Py[p], inv, an[p], asx[p], asy[p], avx[p], avy[p], acx[p], acy[p]);
            if (npass > 0) { PB(0)
            if (npass > 1) { PB(1)
            if (npass > 2) { PB(2)
            if (npass > 3) { PB(3)
            if (npass > 4) { PB(4)
            if (npass > 5) { PB(5)
            if (npass > 6) { PB(6)
            if (npass > 7) { PB(7) } } } } } } } }
#undef PB
        }
        __syncthreads();
    }

    const float ws = w_sep[0], wa = w_ali[0], wc = w_coh[0], wn = w_noise[0];
#pragma unroll
    for (int p = 0; p < MAXP; ++p) {
        if (p < npass) {
            bfly7(an[p], asx[p], asy[p], avx[p], avy[p], acx[p], acy[p]);
            if (lane == 0) {
                const int si = cstart + wid + p * 8;
                const int orig = sidx[si];
                finalize_core(Vx[p], Vy[p], noise[orig], ws, wa, wc, wn,
                              asx[p], asy[p], avx[p], avy[p], acx[p], acy[p],
                              an[p], out, orig);
            }
        }
    }

    // cold overflow path (cell with > 64 boids): direct L2 sweep, never hot
    for (int p = MAXP; cstart + wid + p * 8 < cend; ++p) {
        const int si = cstart + wid + p * 8;
        const float4 I = sorted4[si];
        float n2 = 0, sx = 0, sy = 0, vx = 0, vy = 0, cx2 = 0, cy2 = 0;
        for (int s = 0; s < nseg; ++s) {
            const int js = seg_src[s];
            const int je = js + (seg_dst[s + 1] - seg_dst[s]);
            for (int j0 = js; j0 < je; j0 += 64) {
                const int   idx = j0 + lane;
                const float inv = (idx < je) ? 0.0f : 1e9f;
                const float4 q  = sorted4[(idx < je) ? idx : (je - 1)];
                pair_acc(q, I.x, I.y, inv, n2, sx, sy, vx, vy, cx2, cy2);
            }
        }
        bfly7(n2, sx, sy, vx, vy, cx2, cy2);
        if (lane == 0) {
            const int orig = sidx[si];
            finalize_core(I.z, I.w, noise[orig], ws, wa, wc, wn,
                          sx, sy, vx, vy, cx2, cy2, n2, out, orig);
        }
    }
}

// ================= fallback: proven R5 all-pairs kernel =================
constexpr int FB_BLOCK = 256;
constexpr int FB_TILE  = 2048;

__global__ __launch_bounds__(FB_BLOCK, 4) void boids_allpairs(
    const f32x2* __restrict__ pos, const f32x2* __restrict__ vel,
    const f32x2* __restrict__ noise,
    const float* __restrict__ w_sep, const float* __restrict__ w_ali,
    const float* __restrict__ w_coh, const float* __restrict__ w_noise,
    float* __restrict__ out)
{
    __shared__ f32x4 tile[FB_TILE];
    const int tid  = threadIdx.x;
    const int lane = tid & 63;
    const int wid  = tid >> 6;
    const int i0   = (blockIdx.x * 4 + wid) * 2;
    const f32x2 P0 = pos[i0];
    const f32x2 P1 = pos[i0 + 1];
    float n0 = 0.f, s0x = 0.f, s0y = 0.f, v0x = 0.f, v0y = 0.f, c0x = 0.f, c0y = 0.f;
    float n1 = 0.f, s1x = 0.f, s1y = 0.f, v1x = 0.f, v1y = 0.f, c1x = 0.f, c1y = 0.f;
    for (int t = 0; t < N_BOIDS / FB_TILE; ++t) {
        const f32x4* gp = reinterpret_cast<const f32x4*>(pos) + t * (FB_TILE / 2);
        const f32x4* gv = reinterpret_cast<const f32x4*>(vel) + t * (FB_TILE / 2);
#pragma unroll
        for (int c = 0; c < FB_TILE / 2 / FB_BLOCK; ++c) {
            const int idx  = tid + c * FB_BLOCK;
            const f32x4 pp = gp[idx];
            const f32x4 vv = gv[idx];
            f32x4 t0; t0.x = pp.x; t0.y = pp.y; t0.z = vv.x; t0.w = vv.y;
            f32x4 t1; t1.x = pp.z; t1.y = pp.w; t1.z = vv.z; t1.w = vv.w;
            tile[2 * idx] = t0; tile[2 * idx + 1] = t1;
        }
        __syncthreads();
#pragma unroll 8
        for (int k = 0; k < FB_TILE / 64; ++k) {
            const f32x4 qq = tile[lane + k * 64];
            float4 q; q.x = qq.x; q.y = qq.y; q.z = qq.z; q.w = qq.w;
            pair_acc(q, P0.x, P0.y, 0.0f, n0, s0x, s0y, v0x, v0y, c0x, c0y);
            pair_acc(q, P1.x, P1.y, 0.0f, n1, s1x, s1y, v1x, v1y, c1x, c1y);
        }
        __syncthreads();
    }
    bfly7(n0, s0x, s0y, v0x, v0y, c0x, c0y);
    bfly7(n1, s1x, s1y, v1x, v1y, c1x, c1y);
    if (lane < 2) {
        float sx = s0x, sy = s0y, vx = v0x, vy = v0y, cx = c0x, cy = c0y, cc = n0;
        int i = i0;
        if (lane == 1) {
            sx = s1x; sy = s1y; vx = v1x; vy = v1y; cx = c1x; cy = c1y; cc = n1;
            i = i0 + 1;
        }
        finalize_core(vel[i].x, vel[i].y, noise[i],
                      w_sep[0], w_ali[0], w_coh[0], w_noise[0],
                      sx, sy, vx, vy, cx, cy, cc, out, i);
    }
}

extern "C" void kernel_launch(void* const* d_in, const int* in_sizes, int n_in,
                              void* d_out, int out_size, void* d_ws, size_t ws_size,
                              hipStream_t stream) {
    const float* pos_f   = (const float*)d_in[0];
    const float* vel_f   = (const float*)d_in[1];
    const f32x2* noise   = (const f32x2*)d_in[2];
    const float* w_sep   = (const float*)d_in[3];
    const float* w_ali   = (const float*)d_in[4];
    const float* w_coh   = (const float*)d_in[5];
    const float* w_noise = (const float*)d_in[6];
    float* out = (float*)d_out;

    if (ws_size >= WS_NEED) {
        char* wsb = (char*)d_ws;
        int*    cs      = (int*)(wsb + CS_OFF);
        float4* sorted4 = (float4*)(wsb + SORT_OFF);
        int*    sidx    = (int*)(wsb + SIDX_OFF);
        sort_all<<<NBLK, CHUNK, 0, stream>>>(pos_f, vel_f, cs, sorted4, sidx);
        boids_cell<<<NCELL, 512, 0, stream>>>(
            sorted4, sidx, cs, noise, w_sep, w_ali, w_coh, w_noise, out);
    } else {
        boids_allpairs<<<N_BOIDS / 8, FB_BLOCK, 0, stream>>>(
            (const f32x2*)pos_f, (const f32x2*)vel_f, noise,
            w_sep, w_ali, w_coh, w_noise, out);
    }
}

// Round 11
// 41.614 us; speedup vs baseline: 1.1526x; 1.1526x over previous
//
#include <hip/hip_runtime.h>
#include <math.h>

#define N_BOIDS 8192
typedef float f32x2 __attribute__((ext_vector_type(2)));
typedef float f32x4 __attribute__((ext_vector_type(4)));

// ---- binning
constexpr int   NC    = 16;
constexpr int   NCELL = NC * NC;            // 256
constexpr int   CHUNK = 256;
constexpr int   NBLK  = N_BOIDS / CHUNK;    // 32
constexpr int   MAXP  = 4;                  // i-boids per wave (fast path)
constexpr int   WLCAP = 2368;               // LDS worklist (37.9 KB)
// ws layout
constexpr size_t CS_OFF   = 0;              // 257*4 -> pad 4096
constexpr size_t SORT_OFF = 4096;           // 8192*16
constexpr size_t SIDX_OFF = 135168;         // 8192*4
constexpr size_t WS_NEED  = 167936;

// f32 roundings of the Python doubles 0.02**2 and 0.2**2
constexpr float SEP_R2  = 4.0000000000000008e-04f;
constexpr float PERC_R2 = 4.0000000000000001e-02f;
constexpr float EPSF    = 1e-08f;

__device__ __forceinline__ int cell_of(float px, float py) {
    int cx = (int)(px * 16.0f); cx = cx > 15 ? 15 : (cx < 0 ? 0 : cx);
    int cy = (int)(py * 16.0f); cy = cy > 15 ? 15 : (cy < 0 ? 0 : cy);
    return cy * NC + cx;
}

// ---- fused sort: hist(all) + scan + stable scatter of own chunk (proven R9)
__global__ __launch_bounds__(CHUNK) void sort_all(
    const float* __restrict__ pos, const float* __restrict__ vel,
    int* __restrict__ cs, float4* __restrict__ sorted4, int* __restrict__ sidx)
{
    __shared__ int tot[NCELL];
    __shared__ int part[NCELL];
    __shared__ int scan[NCELL];
    __shared__ int cid[CHUNK];
    const int c = threadIdx.x;
    const int b = blockIdx.x;
    tot[c] = 0; part[c] = 0;
    __syncthreads();
    const int lim = b * CHUNK;
    for (int i = c; i < N_BOIDS; i += CHUNK) {
        const int cc = cell_of(pos[2 * i], pos[2 * i + 1]);
        atomicAdd(&tot[cc], 1);                 // counts only: order-independent
        if (i < lim) atomicAdd(&part[cc], 1);
    }
    __syncthreads();
    scan[c] = tot[c];
    __syncthreads();
#pragma unroll
    for (int off = 1; off < NCELL; off <<= 1) {
        int v = (c >= off) ? scan[c - off] : 0;
        __syncthreads();
        scan[c] += v;
        __syncthreads();
    }
    if (b == 0) {
        cs[c] = scan[c] - tot[c];
        if (c == NCELL - 1) cs[NCELL] = scan[NCELL - 1];
    }
    const int i = lim + c;
    const float px = pos[2 * i], py = pos[2 * i + 1];
    const int myc = cell_of(px, py);
    cid[c] = myc;
    __syncthreads();
    int rank = 0;
    for (int t2 = 0; t2 < c; ++t2) rank += (cid[t2] == myc) ? 1 : 0;
    const int slot = (scan[myc] - tot[myc]) + part[myc] + rank;
    float4 o; o.x = px; o.y = py; o.z = vel[2 * i]; o.w = vel[2 * i + 1];
    sorted4[slot] = o;
    sidx[slot]    = i;
}

// ---- exact 21-instr pair accumulate (bit-identical mask math since R5)
__device__ __forceinline__ void pair_acc(
    const float4& q, float px, float py, float inv,
    float& n, float& sx, float& sy, float& vx, float& vy, float& cx, float& cy)
{
    float dx, dy, ta, tb, m;
    asm("v_sub_f32   %[dx], %[qx], %[px]\n\t"
        "v_sub_f32   %[dy], %[qy], %[py]\n\t"
        "v_rndne_f32 %[ta], %[dx]\n\t"
        "v_rndne_f32 %[tb], %[dy]\n\t"
        "v_sub_f32   %[dx], %[dx], %[ta]\n\t"
        "v_sub_f32   %[dy], %[dy], %[tb]\n\t"
        "v_mul_f32   %[ta], %[dx], %[dx]\n\t"
        "v_mul_f32   %[tb], %[dy], %[dy]\n\t"
        "v_add_f32   %[ta], %[ta], %[tb]\n\t"   // d2, exact RN mul/mul/add
        "v_max_f32   %[ta], %[ta], %[inv]\n\t"  // pad lanes -> 1e9
        "v_cmp_ge_f32 vcc, %[vperc], %[ta]\n\t"
        "v_cndmask_b32 %[m], 0, 1.0, vcc\n\t"
        "v_add_f32   %[n], %[n], %[m]\n\t"
        "v_fmac_f32  %[vx], %[m], %[qz]\n\t"
        "v_fmac_f32  %[vy], %[m], %[qw]\n\t"
        "v_fmac_f32  %[cx], %[m], %[dx]\n\t"
        "v_fmac_f32  %[cy], %[m], %[dy]\n\t"
        "v_cmp_ge_f32 vcc, %[vsep], %[ta]\n\t"
        "v_cndmask_b32 %[m], 0, 1.0, vcc\n\t"
        "v_fma_f32   %[sx], -%[m], %[dx], %[sx]\n\t"
        "v_fma_f32   %[sy], -%[m], %[dy], %[sy]\n\t"
        : [dx] "=&v"(dx), [dy] "=&v"(dy), [ta] "=&v"(ta),
          [tb] "=&v"(tb), [m] "=&v"(m),
          [n] "+v"(n), [sx] "+v"(sx), [sy] "+v"(sy),
          [vx] "+v"(vx), [vy] "+v"(vy), [cx] "+v"(cx), [cy] "+v"(cy)
        : [qx] "v"(q.x), [qy] "v"(q.y), [qz] "v"(q.z), [qw] "v"(q.w),
          [px] "v"(px), [py] "v"(py),
          [vperc] "v"(PERC_R2), [vsep] "v"(SEP_R2), [inv] "v"(inv)
        : "vcc");
}

__device__ __forceinline__ void bfly7(float& a, float& b, float& c, float& d,
                                      float& e, float& f, float& g)
{
#pragma unroll
    for (int m = 1; m < 64; m <<= 1) {
        a += __shfl_xor(a, m); b += __shfl_xor(b, m); c += __shfl_xor(c, m);
        d += __shfl_xor(d, m); e += __shfl_xor(e, m); f += __shfl_xor(f, m);
        g += __shfl_xor(g, m);
    }
}

__device__ __forceinline__ void finalize_core(
    float vix, float viy, const f32x2 nz,
    float ws, float wa, float wc, float wn,
    float sx, float sy, float vx, float vy, float cx, float cy, float cntall,
    float* __restrict__ out, int orig)
{
    const float cnt = cntall - 1.0f;  // remove self (d2==0 passed the mask)
    float ns  = fmaxf(sqrtf(sx * sx + sy * sy), EPSF);
    float ssx = sx / ns, ssy = sy / ns;
    float vax = (vx - vix) / cnt - vix;
    float vay = (vy - viy) / cnt - viy;
    float na  = fmaxf(sqrtf(vax * vax + vay * vay), EPSF);
    float sax = vax / na, say = vay / na;
    float pax = cx / cnt, pay = cy / cnt;
    float nc  = fmaxf(sqrtf(pax * pax + pay * pay), EPSF);
    float scx = pax / nc, scy = pay / nc;
    float ax = ws * ssx + wa * sax + wc * scx;
    float ay = ws * ssy + wa * say + wc * scy;
    ax += wn * nz.x;
    ay += wn * nz.y;
    const float nn = sqrtf(ax * ax + ay * ay);
    if (nn > 1.0f) {
        const float s = 1.0f / fmaxf(nn, EPSF);
        ax *= s; ay *= s;
    }
    out[2 * orig]     = ax;
    out[2 * orig + 1] = ay;
}

// ---- main: 4 blocks per cell (quarter-cells); coalesced LDS worklist
__global__ __launch_bounds__(256, 4) void boids_cell4(
    const float4* __restrict__ sorted4,
    const int* __restrict__ sidx,
    const int* __restrict__ cs,
    const f32x2* __restrict__ noise,
    const float* __restrict__ w_sep, const float* __restrict__ w_ali,
    const float* __restrict__ w_coh, const float* __restrict__ w_noise,
    float* __restrict__ out)
{
    __shared__ int    cs_l[NCELL + 1];
    __shared__ int    seg_src[20], seg_dst[20];
    __shared__ int    nseg_s, total_s;
    __shared__ float4 wl[WLCAP];                  // 37.9 KB

    const int tid  = threadIdx.x;
    const int lane = tid & 63;
    const int wid  = tid >> 6;                    // 0..3

    cs_l[tid] = cs[tid];
    if (tid == 0) cs_l[NCELL] = cs[NCELL];
    __syncthreads();

    const int cellId = blockIdx.x >> 2;
    const int qi     = blockIdx.x & 3;
    const int cx = cellId & (NC - 1), cy = cellId >> 4;
    const int cstart = cs_l[cellId], cend = cs_l[cellId + 1];
    const int n     = cend - cstart;
    const int myst  = cstart + ((n * qi) >> 2);
    const int myend = cstart + ((n * (qi + 1)) >> 2);
    const int mycnt = myend - myst;
    if (mycnt <= 0) return;                       // uniform across block

    if (tid == 0) {
        // exact neighbor disc for reach 0.2002 on a 1/16 grid
        const int HW[9] = {2, 3, 4, 4, 4, 4, 4, 3, 2};
        int ns = 0, tot = 0;
        for (int oy = -4; oy <= 4; ++oy) {
            const int ry = (cy + oy) & (NC - 1);
            const int rb = ry * NC;
            const int hw = HW[oy + 4];
            const int ncl = 2 * hw + 1;
            const int xs = (cx - hw) & (NC - 1);
            const int lA = (ncl < NC - xs) ? ncl : (NC - xs);
            const int sA = cs_l[rb + xs], eA = cs_l[rb + xs + lA];
            if (eA > sA) { seg_src[ns] = sA; seg_dst[ns] = tot; tot += eA - sA; ++ns; }
            const int lB = ncl - lA;
            if (lB > 0) {
                const int sB = cs_l[rb], eB = cs_l[rb + lB];
                if (eB > sB) { seg_src[ns] = sB; seg_dst[ns] = tot; tot += eB - sB; ++ns; }
            }
        }
        nseg_s = ns; total_s = tot; seg_dst[ns] = tot;  // sentinel
    }
    __syncthreads();
    const int nseg = nseg_s, total = total_s;

    int npass = (mycnt - wid + 3) >> 2;
    if (npass < 0) npass = 0;
    if (npass > MAXP) npass = MAXP;

    float Px[MAXP], Py[MAXP], Vx[MAXP], Vy[MAXP];
    float an[MAXP], asx[MAXP], asy[MAXP], avx[MAXP], avy[MAXP], acx[MAXP], acy[MAXP];
#pragma unroll
    for (int p = 0; p < MAXP; ++p) {
        Px[p] = 0.f; Py[p] = 0.f; Vx[p] = 0.f; Vy[p] = 0.f;
        an[p] = 0.f; asx[p] = 0.f; asy[p] = 0.f;
        avx[p] = 0.f; avy[p] = 0.f; acx[p] = 0.f; acy[p] = 0.f;
    }
#pragma unroll
    for (int p = 0; p < MAXP; ++p) {
        if (p < npass) {
            const float4 I = sorted4[myst + wid + p * 4];
            Px[p] = I.x; Py[p] = I.y; Vx[p] = I.z; Vy[p] = I.w;
        }
    }

    for (int base = 0; base < total; base += WLCAP) {
        const int clen = (total - base < WLCAP) ? (total - base) : WLCAP;
        // coalesced per-segment copy (no search, no divergence)
        for (int s = 0; s < nseg; ++s) {
            const int d0 = seg_dst[s], d1 = seg_dst[s + 1];
            const int lo = d0 > base ? d0 : base;
            const int hi = d1 < base + clen ? d1 : base + clen;
            for (int g = lo + tid; g < hi; g += 256)
                wl[g - base] = sorted4[seg_src[s] + (g - d0)];
        }
        __syncthreads();
        for (int j0 = 0; j0 < clen; j0 += 64) {
            const int   idx = j0 + lane;
            const float inv = (idx < clen) ? 0.0f : 1e9f;
            const float4 q  = wl[(idx < clen) ? idx : (clen - 1)];
#define PB(p) pair_acc(q, Px[p], Py[p], inv, an[p], asx[p], asy[p], avx[p], avy[p], acx[p], acy[p]);
            if (npass > 0) { PB(0)
            if (npass > 1) { PB(1)
            if (npass > 2) { PB(2)
            if (npass > 3) { PB(3) } } } }
#undef PB
        }
        __syncthreads();
    }

    const float ws = w_sep[0], wa = w_ali[0], wc = w_coh[0], wn = w_noise[0];
#pragma unroll
    for (int p = 0; p < MAXP; ++p) {
        if (p < npass) {
            bfly7(an[p], asx[p], asy[p], avx[p], avy[p], acx[p], acy[p]);
            if (lane == 0) {
                const int si = myst + wid + p * 4;
                const int orig = sidx[si];
                finalize_core(Vx[p], Vy[p], noise[orig], ws, wa, wc, wn,
                              asx[p], asy[p], avx[p], avy[p], acx[p], acy[p],
                              an[p], out, orig);
            }
        }
    }

    // cold overflow (quarter-cell > 16 boids): direct L2 segment sweep
    for (int p = MAXP; myst + wid + p * 4 < myend; ++p) {
        const int si = myst + wid + p * 4;
        const float4 I = sorted4[si];
        float n2 = 0, sx = 0, sy = 0, vx = 0, vy = 0, cx2 = 0, cy2 = 0;
        for (int s = 0; s < nseg; ++s) {
            const int js = seg_src[s];
            const int je = js + (seg_dst[s + 1] - seg_dst[s]);
            for (int j0 = js; j0 < je; j0 += 64) {
                const int   idx = j0 + lane;
                const float inv = (idx < je) ? 0.0f : 1e9f;
                const float4 q  = sorted4[(idx < je) ? idx : (je - 1)];
                pair_acc(q, I.x, I.y, inv, n2, sx, sy, vx, vy, cx2, cy2);
            }
        }
        bfly7(n2, sx, sy, vx, vy, cx2, cy2);
        if (lane == 0) {
            const int orig = sidx[si];
            finalize_core(I.z, I.w, noise[orig], ws, wa, wc, wn,
                          sx, sy, vx, vy, cx2, cy2, n2, out, orig);
        }
    }
}

// ================= fallback: proven R5 all-pairs kernel =================
constexpr int FB_BLOCK = 256;
constexpr int FB_TILE  = 2048;

__global__ __launch_bounds__(FB_BLOCK, 4) void boids_allpairs(
    const f32x2* __restrict__ pos, const f32x2* __restrict__ vel,
    const f32x2* __restrict__ noise,
    const float* __restrict__ w_sep, const float* __restrict__ w_ali,
    const float* __restrict__ w_coh, const float* __restrict__ w_noise,
    float* __restrict__ out)
{
    __shared__ f32x4 tile[FB_TILE];
    const int tid  = threadIdx.x;
    const int lane = tid & 63;
    const int wid  = tid >> 6;
    const int i0   = (blockIdx.x * 4 + wid) * 2;
    const f32x2 P0 = pos[i0];
    const f32x2 P1 = pos[i0 + 1];
    float n0 = 0.f, s0x = 0.f, s0y = 0.f, v0x = 0.f, v0y = 0.f, c0x = 0.f, c0y = 0.f;
    float n1 = 0.f, s1x = 0.f, s1y = 0.f, v1x = 0.f, v1y = 0.f, c1x = 0.f, c1y = 0.f;
    for (int t = 0; t < N_BOIDS / FB_TILE; ++t) {
        const f32x4* gp = reinterpret_cast<const f32x4*>(pos) + t * (FB_TILE / 2);
        const f32x4* gv = reinterpret_cast<const f32x4*>(vel) + t * (FB_TILE / 2);
#pragma unroll
        for (int c = 0; c < FB_TILE / 2 / FB_BLOCK; ++c) {
            const int idx  = tid + c * FB_BLOCK;
            const f32x4 pp = gp[idx];
            const f32x4 vv = gv[idx];
            f32x4 t0; t0.x = pp.x; t0.y = pp.y; t0.z = vv.x; t0.w = vv.y;
            f32x4 t1; t1.x = pp.z; t1.y = pp.w; t1.z = vv.z; t1.w = vv.w;
            tile[2 * idx] = t0; tile[2 * idx + 1] = t1;
        }
        __syncthreads();
#pragma unroll 8
        for (int k = 0; k < FB_TILE / 64; ++k) {
            const f32x4 qq = tile[lane + k * 64];
            float4 q; q.x = qq.x; q.y = qq.y; q.z = qq.z; q.w = qq.w;
            pair_acc(q, P0.x, P0.y, 0.0f, n0, s0x, s0y, v0x, v0y, c0x, c0y);
            pair_acc(q, P1.x, P1.y, 0.0f, n1, s1x, s1y, v1x, v1y, c1x, c1y);
        }
        __syncthreads();
    }
    bfly7(n0, s0x, s0y, v0x, v0y, c0x, c0y);
    bfly7(n1, s1x, s1y, v1x, v1y, c1x, c1y);
    if (lane < 2) {
        float sx = s0x, sy = s0y, vx = v0x, vy = v0y, cx = c0x, cy = c0y, cc = n0;
        int i = i0;
        if (lane == 1) {
            sx = s1x; sy = s1y; vx = v1x; vy = v1y; cx = c1x; cy = c1y; cc = n1;
            i = i0 + 1;
        }
        finalize_core(vel[i].x, vel[i].y, noise[i],
                      w_sep[0], w_ali[0], w_coh[0], w_noise[0],
                      sx, sy, vx, vy, cx, cy, cc, out, i);
    }
}

extern "C" void kernel_launch(void* const* d_in, const int* in_sizes, int n_in,
                              void* d_out, int out_size, void* d_ws, size_t ws_size,
                              hipStream_t stream) {
    const float* pos_f   = (const float*)d_in[0];
    const float* vel_f   = (const float*)d_in[1];
    const f32x2* noise   = (const f32x2*)d_in[2];
    const float* w_sep   = (const float*)d_in[3];
    const float* w_ali   = (const float*)d_in[4];
    const float* w_coh   = (const float*)d_in[5];
    const float* w_noise = (const float*)d_in[6];
    float* out = (float*)d_out;

    if (ws_size >= WS_NEED) {
        char* wsb = (char*)d_ws;
        int*    cs      = (int*)(wsb + CS_OFF);
        float4* sorted4 = (float4*)(wsb + SORT_OFF);
        int*    sidx    = (int*)(wsb + SIDX_OFF);
        sort_all<<<NBLK, CHUNK, 0, stream>>>(pos_f, vel_f, cs, sorted4, sidx);
        boids_cell4<<<NCELL * 4, 256, 0, stream>>>(
            sorted4, sidx, cs, noise, w_sep, w_ali, w_coh, w_noise, out);
    } else {
        boids_allpairs<<<N_BOIDS / 8, FB_BLOCK, 0, stream>>>(
            (const f32x2*)pos_f, (const f32x2*)vel_f, noise,
            w_sep, w_ali, w_coh, w_noise, out);
    }
}

// Round 12
// 34.154 us; speedup vs baseline: 1.4044x; 1.2184x over previous
//
#include <hip/hip_runtime.h>
#include <math.h>

#define N_BOIDS 8192
typedef float f32x2 __attribute__((ext_vector_type(2)));
typedef float f32x4 __attribute__((ext_vector_type(4)));

constexpr int   BLOCK           = 256;
constexpr int   WAVES_PER_BLOCK = BLOCK / 64;                   // 4
constexpr int   I_PER_WAVE      = 2;                            // boids per wave
constexpr int   I_PER_BLOCK     = WAVES_PER_BLOCK * I_PER_WAVE; // 8
constexpr int   TILE            = 2048;                         // j-boids per LDS tile
constexpr int   NTILES          = N_BOIDS / TILE;               // 4
// f32 roundings of the Python doubles 0.02**2 and 0.2**2
constexpr float SEP_R2  = 4.0000000000000008e-04f;
constexpr float PERC_R2 = 4.0000000000000001e-02f;
constexpr float EPSF    = 1e-08f;

__device__ __forceinline__ void finalize_boid(
    int i, const f32x2* __restrict__ vel, const f32x2* __restrict__ noise,
    float ws, float wa, float wc, float wn,
    float sx, float sy, float vx, float vy, float cx, float cy, float cntall,
    float* __restrict__ out)
{
    const float cnt = cntall - 1.0f;  // remove self (d2 == 0 passed the mask)

    // separation
    float ns  = fmaxf(sqrtf(sx * sx + sy * sy), EPSF);
    float ssx = sx / ns, ssy = sy / ns;

    // alignment: (sum incl. self - vi)/cnt - vi
    const f32x2 vi = vel[i];
    float vax = (vx - vi.x) / cnt - vi.x;
    float vay = (vy - vi.y) / cnt - vi.y;
    float na  = fmaxf(sqrtf(vax * vax + vay * vay), EPSF);
    float sax = vax / na, say = vay / na;

    // cohesion (self added exactly 0)
    float pax = cx / cnt, pay = cy / cnt;
    float nc  = fmaxf(sqrtf(pax * pax + pay * pay), EPSF);
    float scx = pax / nc, scy = pay / nc;

    float ax = ws * ssx + wa * sax + wc * scx;
    float ay = ws * ssy + wa * say + wc * scy;
    const f32x2 nz = noise[i];
    ax += wn * nz.x;
    ay += wn * nz.y;

    const float nn = sqrtf(ax * ax + ay * ay);
    if (nn > 1.0f) {
        const float s = 1.0f / fmaxf(nn, EPSF);
        ax *= s;
        ay *= s;
    }
    out[2 * i]     = ax;
    out[2 * i + 1] = ay;
}

__global__ __launch_bounds__(BLOCK, 4) void boids_kernel(
    const f32x2* __restrict__ pos,
    const f32x2* __restrict__ vel,
    const f32x2* __restrict__ noise,
    const float* __restrict__ w_sep,
    const float* __restrict__ w_ali,
    const float* __restrict__ w_coh,
    const float* __restrict__ w_noise,
    float* __restrict__ out)
{
    __shared__ f32x4 tile[TILE];  // (px, py, vx, vy) per j-boid: 32 KB

    const int tid  = threadIdx.x;
    const int lane = tid & 63;
    const int wid  = tid >> 6;
    const int i0   = (blockIdx.x * WAVES_PER_BLOCK + wid) * I_PER_WAVE;

    const f32x2 P0 = pos[i0];
    const f32x2 P1 = pos[i0 + 1];
    const float vperc = PERC_R2;
    const float vsep  = SEP_R2;

    float n0 = 0.f, s0x = 0.f, s0y = 0.f, v0x = 0.f, v0y = 0.f, c0x = 0.f, c0y = 0.f;
    float n1 = 0.f, s1x = 0.f, s1y = 0.f, v1x = 0.f, v1y = 0.f, c1x = 0.f, c1y = 0.f;

    for (int t = 0; t < NTILES; ++t) {
        // stage TILE boids: pos+vel interleaved as (px,py,vx,vy)
        const f32x4* gp = reinterpret_cast<const f32x4*>(pos) + t * (TILE / 2);
        const f32x4* gv = reinterpret_cast<const f32x4*>(vel) + t * (TILE / 2);
#pragma unroll
        for (int c = 0; c < TILE / 2 / BLOCK; ++c) {  // 4 iters
            const int idx  = tid + c * BLOCK;
            const f32x4 pp = gp[idx];   // positions of boids 2*idx, 2*idx+1
            const f32x4 vv = gv[idx];   // their velocities
            f32x4 t0; t0.x = pp.x; t0.y = pp.y; t0.z = vv.x; t0.w = vv.y;
            f32x4 t1; t1.x = pp.z; t1.y = pp.w; t1.z = vv.z; t1.w = vv.w;
            tile[2 * idx]     = t0;
            tile[2 * idx + 1] = t1;
        }
        __syncthreads();

#pragma unroll 8
        for (int k = 0; k < TILE / 64; ++k) {  // 32 iters
            const f32x4 q = tile[lane + k * 64];
            float dx, dy, ta, tb, m;
            // Exactly 40 VALU instrs for the 2 boids; masks via vcc,
            // inline 0/1.0 consts, neg-modifier fma for separation.
            asm(
                // ---- boid 0
                "v_sub_f32   %[dx], %[qx], %[p0x]\n\t"
                "v_sub_f32   %[dy], %[qy], %[p0y]\n\t"
                "v_rndne_f32 %[ta], %[dx]\n\t"
                "v_rndne_f32 %[tb], %[dy]\n\t"
                "v_sub_f32   %[dx], %[dx], %[ta]\n\t"
                "v_sub_f32   %[dy], %[dy], %[tb]\n\t"
                "v_mul_f32   %[ta], %[dx], %[dx]\n\t"
                "v_mul_f32   %[tb], %[dy], %[dy]\n\t"
                "v_add_f32   %[ta], %[ta], %[tb]\n\t"
                "v_cmp_ge_f32 vcc, %[vperc], %[ta]\n\t"
                "v_cndmask_b32 %[m], 0, 1.0, vcc\n\t"
                "v_add_f32   %[n0], %[n0], %[m]\n\t"
                "v_fmac_f32  %[v0x], %[m], %[qz]\n\t"
                "v_fmac_f32  %[v0y], %[m], %[qw]\n\t"
                "v_fmac_f32  %[c0x], %[m], %[dx]\n\t"
                "v_fmac_f32  %[c0y], %[m], %[dy]\n\t"
                "v_cmp_ge_f32 vcc, %[vsep], %[ta]\n\t"
                "v_cndmask_b32 %[m], 0, 1.0, vcc\n\t"
                "v_fma_f32   %[s0x], -%[m], %[dx], %[s0x]\n\t"
                "v_fma_f32   %[s0y], -%[m], %[dy], %[s0y]\n\t"
                // ---- boid 1
                "v_sub_f32   %[dx], %[qx], %[p1x]\n\t"
                "v_sub_f32   %[dy], %[qy], %[p1y]\n\t"
                "v_rndne_f32 %[ta], %[dx]\n\t"
                "v_rndne_f32 %[tb], %[dy]\n\t"
                "v_sub_f32   %[dx], %[dx], %[ta]\n\t"
                "v_sub_f32   %[dy], %[dy], %[tb]\n\t"
                "v_mul_f32   %[ta], %[dx], %[dx]\n\t"
                "v_mul_f32   %[tb], %[dy], %[dy]\n\t"
                "v_add_f32   %[ta], %[ta], %[tb]\n\t"
                "v_cmp_ge_f32 vcc, %[vperc], %[ta]\n\t"
                "v_cndmask_b32 %[m], 0, 1.0, vcc\n\t"
                "v_add_f32   %[n1], %[n1], %[m]\n\t"
                "v_fmac_f32  %[v1x], %[m], %[qz]\n\t"
                "v_fmac_f32  %[v1y], %[m], %[qw]\n\t"
                "v_fmac_f32  %[c1x], %[m], %[dx]\n\t"
                "v_fmac_f32  %[c1y], %[m], %[dy]\n\t"
                "v_cmp_ge_f32 vcc, %[vsep], %[ta]\n\t"
                "v_cndmask_b32 %[m], 0, 1.0, vcc\n\t"
                "v_fma_f32   %[s1x], -%[m], %[dx], %[s1x]\n\t"
                "v_fma_f32   %[s1y], -%[m], %[dy], %[s1y]\n\t"
                : [dx] "=&v"(dx), [dy] "=&v"(dy), [ta] "=&v"(ta),
                  [tb] "=&v"(tb), [m] "=&v"(m),
                  [n0] "+v"(n0), [s0x] "+v"(s0x), [s0y] "+v"(s0y),
                  [v0x] "+v"(v0x), [v0y] "+v"(v0y), [c0x] "+v"(c0x), [c0y] "+v"(c0y),
                  [n1] "+v"(n1), [s1x] "+v"(s1x), [s1y] "+v"(s1y),
                  [v1x] "+v"(v1x), [v1y] "+v"(v1y), [c1x] "+v"(c1x), [c1y] "+v"(c1y)
                : [qx] "v"(q.x), [qy] "v"(q.y), [qz] "v"(q.z), [qw] "v"(q.w),
                  [p0x] "v"(P0.x), [p0y] "v"(P0.y),
                  [p1x] "v"(P1.x), [p1y] "v"(P1.y),
                  [vperc] "v"(vperc), [vsep] "v"(vsep)
                : "vcc");
        }
        __syncthreads();
    }

    // full-wave butterfly reduction (all 64 lanes end with totals)
#pragma unroll
    for (int mlev = 1; mlev < 64; mlev <<= 1) {
        n0  += __shfl_xor(n0,  mlev);
        s0x += __shfl_xor(s0x, mlev);  s0y += __shfl_xor(s0y, mlev);
        v0x += __shfl_xor(v0x, mlev);  v0y += __shfl_xor(v0y, mlev);
        c0x += __shfl_xor(c0x, mlev);  c0y += __shfl_xor(c0y, mlev);
        n1  += __shfl_xor(n1,  mlev);
        s1x += __shfl_xor(s1x, mlev);  s1y += __shfl_xor(s1y, mlev);
        v1x += __shfl_xor(v1x, mlev);  v1y += __shfl_xor(v1y, mlev);
        c1x += __shfl_xor(c1x, mlev);  c1y += __shfl_xor(c1y, mlev);
    }

    // lanes 0..1 each finalize one boid (parallel epilogue)
    float sx = s0x, sy = s0y, vx = v0x, vy = v0y, cx = c0x, cy = c0y, cc = n0;
    if (lane == 1) {
        sx = s1x; sy = s1y; vx = v1x; vy = v1y; cx = c1x; cy = c1y; cc = n1;
    }
    if (lane < I_PER_WAVE) {
        const float ws = w_sep[0], wa = w_ali[0], wc = w_coh[0], wn = w_noise[0];
        finalize_boid(i0 + lane, vel, noise, ws, wa, wc, wn,
                      sx, sy, vx, vy, cx, cy, cc, out);
    }
}

extern "C" void kernel_launch(void* const* d_in, const int* in_sizes, int n_in,
                              void* d_out, int out_size, void* d_ws, size_t ws_size,
                              hipStream_t stream) {
    const f32x2* pos     = (const f32x2*)d_in[0];
    const f32x2* vel     = (const f32x2*)d_in[1];
    const f32x2* noise   = (const f32x2*)d_in[2];
    const float* w_sep   = (const float*)d_in[3];
    const float* w_ali   = (const float*)d_in[4];
    const float* w_coh   = (const float*)d_in[5];
    const float* w_noise = (const float*)d_in[6];
    float* out = (float*)d_out;

    const int grid = N_BOIDS / I_PER_BLOCK;  // 1024 blocks
    boids_kernel<<<grid, BLOCK, 0, stream>>>(pos, vel, noise, w_sep, w_ali,
                                             w_coh, w_noise, out);
}